// Round 1
// baseline (1808.862 us; speedup 1.0000x reference)
//
#include <hip/hip_runtime.h>
#include <hip/hip_bf16.h>
#include <stddef.h>

typedef unsigned short ushort_t;
typedef __bf16 bf16x8 __attribute__((ext_vector_type(8)));
typedef float  f32x4  __attribute__((ext_vector_type(4)));

#define GAS __attribute__((address_space(1)))
#define LAS __attribute__((address_space(3)))

__device__ __forceinline__ ushort_t f2bf(float f) {
    union { float f; unsigned u; } v; v.f = f;
    unsigned r = v.u + 0x7fffu + ((v.u >> 16) & 1u);   // RNE
    return (ushort_t)(r >> 16);
}

__device__ __forceinline__ float gelu_tanh(float x) {
    // jax.nn.gelu default: approximate=True (tanh form)
    float x3 = x * x * x;
    float t = tanhf(0.7978845608028654f * (x + 0.044715f * x3));
    return 0.5f * x * (1.0f + t);
}

__device__ __forceinline__ void gload_lds16(const ushort_t* g, ushort_t* l) {
    // 16B per lane; LDS dest = wave-uniform base + lane*16 (HW rule)
    __builtin_amdgcn_global_load_lds((const GAS void*)g, (LAS void*)l, 16, 0, 0);
}

// ---------------- phase A: x fp32 -> bf16, fused mean-pool partials ----------------
// grid (16 b, 16 chunk), block 256. chunk = 64 rows of N.
__global__ __launch_bounds__(256) void k_convert_x_pool(const float* __restrict__ x,
                                                        ushort_t* __restrict__ Xbf,
                                                        float* __restrict__ part) {
    int b = blockIdx.x, c = blockIdx.y, t = threadIdx.x;
    int d = t * 4;
    const float* xp = x + ((size_t)b * 1024 + (size_t)c * 64) * 1024;
    ushort_t* op = Xbf + ((size_t)b * 1024 + (size_t)c * 64) * 1024;
    float s0 = 0, s1 = 0, s2 = 0, s3 = 0;
    for (int n = 0; n < 64; ++n) {
        float4 v = *(const float4*)(xp + (size_t)n * 1024 + d);
        s0 += v.x; s1 += v.y; s2 += v.z; s3 += v.w;
        ushort4 o; o.x = f2bf(v.x); o.y = f2bf(v.y); o.z = f2bf(v.z); o.w = f2bf(v.w);
        *(ushort4*)(op + (size_t)n * 1024 + d) = o;
    }
    float4 s; s.x = s0; s.y = s1; s.z = s2; s.w = s3;
    *(float4*)(part + ((size_t)b * 16 + c) * 1024 + d) = s;
}

// ---------------- router: one block per batch ----------------
// writes eidx[2b..], gsw[2b..] where gsw = (1-a) * renormalized top-2 gate
__global__ __launch_bounds__(256) void k_router(const float* __restrict__ part,
                                                const float* __restrict__ w_gate,
                                                const float* __restrict__ b_gate,
                                                const float* __restrict__ alpha,
                                                int* __restrict__ eidx,
                                                float* __restrict__ gsw) {
    __shared__ float red[8 * 256];
    int b = blockIdx.x, t = threadIdx.x;
    float le[8];
#pragma unroll
    for (int e = 0; e < 8; ++e) le[e] = 0.f;
    for (int i = 0; i < 4; ++i) {
        int d = t + i * 256;
        float s = 0.f;
#pragma unroll
        for (int c = 0; c < 16; ++c) s += part[((size_t)b * 16 + c) * 1024 + d];
        s *= (1.0f / 1024.0f);  // mean over N
#pragma unroll
        for (int e = 0; e < 8; ++e) le[e] += s * w_gate[(size_t)d * 8 + e];
    }
#pragma unroll
    for (int e = 0; e < 8; ++e) red[e * 256 + t] = le[e];
    __syncthreads();
    for (int s2 = 128; s2 > 0; s2 >>= 1) {
        if (t < s2)
#pragma unroll
            for (int e = 0; e < 8; ++e) red[e * 256 + t] += red[e * 256 + t + s2];
        __syncthreads();
    }
    if (t == 0) {
        float lg[8];
#pragma unroll
        for (int e = 0; e < 8; ++e) lg[e] = red[e * 256] + b_gate[e];
        float mx = lg[0];
#pragma unroll
        for (int e = 1; e < 8; ++e) mx = fmaxf(mx, lg[e]);
        float pe[8];
#pragma unroll
        for (int e = 0; e < 8; ++e) pe[e] = expf(lg[e] - mx);
        int i0 = 0;
        for (int e = 1; e < 8; ++e) if (pe[e] > pe[i0]) i0 = e;     // strict > : ties -> lower idx
        int i1 = -1;
        for (int e = 0; e < 8; ++e) { if (e == i0) continue; if (i1 < 0 || pe[e] > pe[i1]) i1 = e; }
        float a = fminf(fmaxf(alpha[0], 0.1f), 1.0f);
        float inv = (1.0f - a) / (pe[i0] + pe[i1]);
        eidx[2 * b] = i0; eidx[2 * b + 1] = i1;
        gsw[2 * b] = pe[i0] * inv; gsw[2 * b + 1] = pe[i1] * inv;
    }
}

// ---------------- transpose+convert: src fp32 [Z][R][C] -> dst bf16 [Z][C][R] ----------------
// grid (C/64, R/64, Z), block 256
__global__ __launch_bounds__(256) void k_transpose_cvt(const float* __restrict__ src,
                                                       ushort_t* __restrict__ dst,
                                                       int R, int C) {
    __shared__ float tile[64][65];
    int z = blockIdx.z;
    const float* s = src + (size_t)z * R * C;
    ushort_t* d = dst + (size_t)z * R * C;
    int c0 = blockIdx.x * 64, r0 = blockIdx.y * 64;
    int t = threadIdx.x;
    int tc = (t & 15) * 4, tr = t >> 4;
#pragma unroll
    for (int i = 0; i < 4; ++i) {
        int r = tr + i * 16;
        float4 v = *(const float4*)(s + (size_t)(r0 + r) * C + c0 + tc);
        tile[r][tc] = v.x; tile[r][tc + 1] = v.y; tile[r][tc + 2] = v.z; tile[r][tc + 3] = v.w;
    }
    __syncthreads();
    int wc = t >> 2, wr = (t & 3) * 16;
#pragma unroll
    for (int i = 0; i < 4; ++i) {
        ushort4 o;
        o.x = f2bf(tile[wr + i * 4 + 0][wc]);
        o.y = f2bf(tile[wr + i * 4 + 1][wc]);
        o.z = f2bf(tile[wr + i * 4 + 2][wc]);
        o.w = f2bf(tile[wr + i * 4 + 3][wc]);
        *(ushort4*)(d + (size_t)(c0 + wc) * R + r0 + wr + i * 4) = o;
    }
}

// ---------------- GEMM core: C128x128 += A[M][K] * Bt[N][K]^T, m97 structure ----------------
template <int NSEG, typename Epi>
__device__ __forceinline__ void gemm128(const ushort_t* A0, const ushort_t* A1,
                                        const ushort_t* B0, const ushort_t* B1,
                                        int segK, int m0, int n0, Epi epi) {
    __shared__ ushort_t lA[128 * 32];
    __shared__ ushort_t lB[128 * 32];
    const int tid = threadIdx.x;
    const int lane = tid & 63;
    const int wave = tid >> 6;
    const int quad = lane >> 4;
    const int l15 = lane & 15;
    const int wm = wave >> 1, wn = wave & 1;
    const int srow = wave * 16 + (lane >> 2);   // staging row, inst 0
    const int scg8 = (lane & 3) * 8;            // staging k-subgroup (8 bf16 = 16B)

    ushort_t* lA0 = lA + wave * 512;
    ushort_t* lA1 = lA + 2048 + wave * 512;
    ushort_t* lB0 = lB + wave * 512;
    ushort_t* lB1 = lB + 2048 + wave * 512;

    f32x4 acc[4][4] = {};
    const int steps = segK >> 5;

#pragma unroll 1
    for (int seg = 0; seg < NSEG; ++seg) {
        const ushort_t* A = (NSEG == 2 && seg == 1) ? A1 : A0;
        const ushort_t* B = (NSEG == 2 && seg == 1) ? B1 : B0;
        const ushort_t* ga0 = A + (size_t)(m0 + srow) * segK + scg8;
        const ushort_t* ga1 = A + (size_t)(m0 + srow + 64) * segK + scg8;
        const ushort_t* gb0 = B + (size_t)(n0 + srow) * segK + scg8;
        const ushort_t* gb1 = B + (size_t)(n0 + srow + 64) * segK + scg8;
#pragma unroll 1
        for (int kt = 0; kt < steps; ++kt) {
            gload_lds16(ga0, lA0);
            gload_lds16(ga1, lA1);
            gload_lds16(gb0, lB0);
            gload_lds16(gb1, lB1);
            ga0 += 32; ga1 += 32; gb0 += 32; gb1 += 32;
            __syncthreads();   // drains vmcnt -> tiles visible
            bf16x8 af[4], bfr[4];
            const bf16x8* pA = (const bf16x8*)lA;
            const bf16x8* pB = (const bf16x8*)lB;
#pragma unroll
            for (int mi = 0; mi < 4; ++mi) af[mi] = pA[(wm * 64 + mi * 16 + l15) * 4 + quad];
#pragma unroll
            for (int ni = 0; ni < 4; ++ni) bfr[ni] = pB[(wn * 64 + ni * 16 + l15) * 4 + quad];
#pragma unroll
            for (int mi = 0; mi < 4; ++mi)
#pragma unroll
                for (int ni = 0; ni < 4; ++ni)
                    acc[mi][ni] = __builtin_amdgcn_mfma_f32_16x16x32_bf16(af[mi], bfr[ni], acc[mi][ni], 0, 0, 0);
            __syncthreads();   // all waves done reading before next stage
        }
    }
    // C/D layout: col = lane&15, row = quad*4 + reg (verified m89/m91)
#pragma unroll
    for (int mi = 0; mi < 4; ++mi)
#pragma unroll
        for (int ni = 0; ni < 4; ++ni)
            epi(m0 + wm * 64 + mi * 16 + quad * 4, n0 + wn * 64 + ni * 16 + l15, acc[mi][ni]);
}

// epilogues
struct EpiGeluStore {   // phases B & D: bf16 store of scale*gelu(acc+bias[col])
    ushort_t* H; int ldh; const float* bias; float scale;
    __device__ void operator()(int r, int c, f32x4 v) const {
        float bc = bias[c];
#pragma unroll
        for (int i = 0; i < 4; ++i)
            H[(size_t)(r + i) * ldh + c] = f2bf(scale * gelu_tanh(v[i] + bc));
    }
};
struct EpiMainOut {     // phase C: out = a*(acc+b2m[col])
    float* out; const float* bias; float a;
    __device__ void operator()(int r, int c, f32x4 v) const {
        float bc = bias[c];
#pragma unroll
        for (int i = 0; i < 4; ++i) out[(size_t)(r + i) * 1024 + c] = a * (v[i] + bc);
    }
};
struct EpiExpertOut {   // phase E: out += acc + g0*b2e0[col] + g1*b2e1[col]  (g includes (1-a))
    float* out; const float* b0; const float* b1; float g0, g1;
    __device__ void operator()(int r, int c, f32x4 v) const {
        float bc = g0 * b0[c] + g1 * b1[c];
#pragma unroll
        for (int i = 0; i < 4; ++i) out[(size_t)(r + i) * 1024 + c] += v[i] + bc;
    }
};

// ---------------- phase kernels ----------------
// B: Hm = gelu(Xbf @ W1mT^T + b1m)   M=16384 N=4096 K=1024, grid 4096
__global__ __launch_bounds__(256) void k_gemm_main1(const ushort_t* __restrict__ Xbf,
                                                    const ushort_t* __restrict__ W1mT,
                                                    const float* __restrict__ b1m,
                                                    ushort_t* __restrict__ Hm) {
    int tn = blockIdx.x & 31, tm = blockIdx.x >> 5;
    EpiGeluStore epi{Hm, 4096, b1m, 1.0f};
    gemm128<1>(Xbf, Xbf, W1mT, W1mT, 1024, tm * 128, tn * 128, epi);
}
// C: out = a*(Hm @ W2mT^T + b2m)     M=16384 N=1024 K=4096, grid 1024
__global__ __launch_bounds__(256) void k_gemm_main2(const ushort_t* __restrict__ Hm,
                                                    const ushort_t* __restrict__ W2mT,
                                                    const float* __restrict__ b2m,
                                                    const float* __restrict__ alpha,
                                                    float* __restrict__ out) {
    int tn = blockIdx.x & 7, tm = blockIdx.x >> 3;
    float a = fminf(fmaxf(alpha[0], 0.1f), 1.0f);
    EpiMainOut epi{out, b2m, a};
    gemm128<1>(Hm, Hm, W2mT, W2mT, 4096, tm * 128, tn * 128, epi);
}
// D: He[j] = gsw[j]*gelu(Xbf[b] @ W1eT[e]^T + b1e[e])  M=1024 N=4096 K=1024, grid (256,32)
__global__ __launch_bounds__(256) void k_gemm_exp1(const ushort_t* __restrict__ Xbf,
                                                   const ushort_t* __restrict__ W1eT,
                                                   const float* __restrict__ b1e,
                                                   const int* __restrict__ eidx,
                                                   const float* __restrict__ gsw,
                                                   ushort_t* __restrict__ He) {
    int j = blockIdx.y, b = j >> 1;
    int e = eidx[j];
    float gs = gsw[j];
    int tn = blockIdx.x & 31, tm = blockIdx.x >> 5;
    const ushort_t* A = Xbf + (size_t)b * 1024 * 1024;
    const ushort_t* B = W1eT + (size_t)e * 4096 * 1024;
    EpiGeluStore epi{He + (size_t)j * 1024 * 4096, 4096, b1e + (size_t)e * 4096, gs};
    gemm128<1>(A, A, B, B, 1024, tm * 128, tn * 128, epi);
}
// E: out[b] += sum_k He[b,k] @ W2eT[ek]^T + gs_k*b2e[ek]   M=1024 N=1024 K=2x4096, grid (64,16)
__global__ __launch_bounds__(256) void k_gemm_exp2(const ushort_t* __restrict__ He,
                                                   const ushort_t* __restrict__ W2eT,
                                                   const float* __restrict__ b2e,
                                                   const int* __restrict__ eidx,
                                                   const float* __restrict__ gsw,
                                                   float* __restrict__ out) {
    int b = blockIdx.y;
    int e0 = eidx[2 * b], e1 = eidx[2 * b + 1];
    int tn = blockIdx.x & 7, tm = blockIdx.x >> 3;
    EpiExpertOut epi{out + (size_t)b * 1024 * 1024,
                     b2e + (size_t)e0 * 1024, b2e + (size_t)e1 * 1024,
                     gsw[2 * b], gsw[2 * b + 1]};
    gemm128<2>(He + (size_t)(2 * b) * 1024 * 4096, He + (size_t)(2 * b + 1) * 1024 * 4096,
               W2eT + (size_t)e0 * 1024 * 4096, W2eT + (size_t)e1 * 1024 * 4096,
               4096, tm * 128, tn * 128, epi);
}

extern "C" void kernel_launch(void* const* d_in, const int* in_sizes, int n_in,
                              void* d_out, int out_size, void* d_ws, size_t ws_size,
                              hipStream_t stream) {
    const float* x      = (const float*)d_in[0];
    const float* alpha  = (const float*)d_in[1];
    const float* w_gate = (const float*)d_in[2];
    const float* b_gate = (const float*)d_in[3];
    const float* W1m    = (const float*)d_in[4];
    const float* b1m    = (const float*)d_in[5];
    const float* W2m    = (const float*)d_in[6];
    const float* b2m    = (const float*)d_in[7];
    const float* W1e    = (const float*)d_in[8];
    const float* b1e    = (const float*)d_in[9];
    const float* W2e    = (const float*)d_in[10];
    const float* b2e    = (const float*)d_in[11];
    float* out = (float*)d_out;

    char* ws = (char*)d_ws;
    size_t off = 0;
    ushort_t* Xbf  = (ushort_t*)(ws + off); off += (size_t)16384 * 1024 * 2;     // 33.5 MB
    ushort_t* W1mT = (ushort_t*)(ws + off); off += (size_t)4096 * 1024 * 2;      // 8.4 MB
    ushort_t* W2mT = (ushort_t*)(ws + off); off += (size_t)4096 * 1024 * 2;      // 8.4 MB
    ushort_t* W1eT = (ushort_t*)(ws + off); off += (size_t)8 * 4096 * 1024 * 2;  // 67 MB
    ushort_t* W2eT = (ushort_t*)(ws + off); off += (size_t)8 * 4096 * 1024 * 2;  // 67 MB
    float*    part = (float*)(ws + off);    off += (size_t)16 * 16 * 1024 * 4;   // 1 MB
    int*      eidx = (int*)(ws + off);      off += 256;
    float*    gsw  = (float*)(ws + off);    off += 256;
    ushort_t* He   = (ushort_t*)(ws + off);                                      // 268 MB
    ushort_t* Hm   = He;  // alias: Hm dead (after main2) before He written (exp1)
    off += (size_t)32 * 1024 * 4096 * 2;
    if (ws_size < off) return;  // insufficient workspace -> leave output zero (clear failure signature)

    k_convert_x_pool<<<dim3(16, 16), 256, 0, stream>>>(x, Xbf, part);
    k_router<<<16, 256, 0, stream>>>(part, w_gate, b_gate, alpha, eidx, gsw);
    k_transpose_cvt<<<dim3(64, 16, 1), 256, 0, stream>>>(W1m, W1mT, 1024, 4096);
    k_transpose_cvt<<<dim3(16, 64, 1), 256, 0, stream>>>(W2m, W2mT, 4096, 1024);
    k_transpose_cvt<<<dim3(64, 16, 8), 256, 0, stream>>>(W1e, W1eT, 1024, 4096);
    k_transpose_cvt<<<dim3(16, 64, 8), 256, 0, stream>>>(W2e, W2eT, 4096, 1024);
    k_gemm_main1<<<4096, 256, 0, stream>>>(Xbf, W1mT, b1m, Hm);
    k_gemm_main2<<<1024, 256, 0, stream>>>(Hm, W2mT, b2m, alpha, out);
    k_gemm_exp1<<<dim3(256, 32), 256, 0, stream>>>(Xbf, W1eT, b1e, eidx, gsw, He);
    k_gemm_exp2<<<dim3(64, 16), 256, 0, stream>>>(He, W2eT, b2e, eidx, gsw, out);
}

// Round 2
// 1574.263 us; speedup vs baseline: 1.1490x; 1.1490x over previous
//
#include <hip/hip_runtime.h>
#include <hip/hip_bf16.h>
#include <stddef.h>

typedef unsigned short ushort_t;
typedef __bf16 bf16x8 __attribute__((ext_vector_type(8)));
typedef float  f32x4  __attribute__((ext_vector_type(4)));

#define GAS __attribute__((address_space(1)))
#define LAS __attribute__((address_space(3)))

__device__ __forceinline__ ushort_t f2bf(float f) {
    union { float f; unsigned u; } v; v.f = f;
    unsigned r = v.u + 0x7fffu + ((v.u >> 16) & 1u);   // RNE
    return (ushort_t)(r >> 16);
}

__device__ __forceinline__ float gelu_tanh(float x) {
    float x3 = x * x * x;
    float t = tanhf(0.7978845608028654f * (x + 0.044715f * x3));
    return 0.5f * x * (1.0f + t);
}

__device__ __forceinline__ void gload_lds16(const ushort_t* g, ushort_t* l) {
    __builtin_amdgcn_global_load_lds((const GAS void*)g, (LAS void*)l, 16, 0, 0);
}

// ---------------- phase A: x fp32 -> bf16, fused mean-pool partials ----------------
__global__ __launch_bounds__(256) void k_convert_x_pool(const float* __restrict__ x,
                                                        ushort_t* __restrict__ Xbf,
                                                        float* __restrict__ part) {
    int b = blockIdx.x, c = blockIdx.y, t = threadIdx.x;
    int d = t * 4;
    const float* xp = x + ((size_t)b * 1024 + (size_t)c * 64) * 1024;
    ushort_t* op = Xbf + ((size_t)b * 1024 + (size_t)c * 64) * 1024;
    float s0 = 0, s1 = 0, s2 = 0, s3 = 0;
    for (int n = 0; n < 64; ++n) {
        float4 v = *(const float4*)(xp + (size_t)n * 1024 + d);
        s0 += v.x; s1 += v.y; s2 += v.z; s3 += v.w;
        ushort4 o; o.x = f2bf(v.x); o.y = f2bf(v.y); o.z = f2bf(v.z); o.w = f2bf(v.w);
        *(ushort4*)(op + (size_t)n * 1024 + d) = o;
    }
    float4 s; s.x = s0; s.y = s1; s.z = s2; s.w = s3;
    *(float4*)(part + ((size_t)b * 16 + c) * 1024 + d) = s;
}

// ---------------- router ----------------
__global__ __launch_bounds__(256) void k_router(const float* __restrict__ part,
                                                const float* __restrict__ w_gate,
                                                const float* __restrict__ b_gate,
                                                const float* __restrict__ alpha,
                                                int* __restrict__ eidx,
                                                float* __restrict__ gsw) {
    __shared__ float red[8 * 256];
    int b = blockIdx.x, t = threadIdx.x;
    float le[8];
#pragma unroll
    for (int e = 0; e < 8; ++e) le[e] = 0.f;
    for (int i = 0; i < 4; ++i) {
        int d = t + i * 256;
        float s = 0.f;
#pragma unroll
        for (int c = 0; c < 16; ++c) s += part[((size_t)b * 16 + c) * 1024 + d];
        s *= (1.0f / 1024.0f);
#pragma unroll
        for (int e = 0; e < 8; ++e) le[e] += s * w_gate[(size_t)d * 8 + e];
    }
#pragma unroll
    for (int e = 0; e < 8; ++e) red[e * 256 + t] = le[e];
    __syncthreads();
    for (int s2 = 128; s2 > 0; s2 >>= 1) {
        if (t < s2)
#pragma unroll
            for (int e = 0; e < 8; ++e) red[e * 256 + t] += red[e * 256 + t + s2];
        __syncthreads();
    }
    if (t == 0) {
        float lg[8];
#pragma unroll
        for (int e = 0; e < 8; ++e) lg[e] = red[e * 256] + b_gate[e];
        float mx = lg[0];
#pragma unroll
        for (int e = 1; e < 8; ++e) mx = fmaxf(mx, lg[e]);
        float pe[8];
#pragma unroll
        for (int e = 0; e < 8; ++e) pe[e] = expf(lg[e] - mx);
        int i0 = 0;
        for (int e = 1; e < 8; ++e) if (pe[e] > pe[i0]) i0 = e;
        int i1 = -1;
        for (int e = 0; e < 8; ++e) { if (e == i0) continue; if (i1 < 0 || pe[e] > pe[i1]) i1 = e; }
        float a = fminf(fmaxf(alpha[0], 0.1f), 1.0f);
        float inv = (1.0f - a) / (pe[i0] + pe[i1]);
        eidx[2 * b] = i0; eidx[2 * b + 1] = i1;
        gsw[2 * b] = pe[i0] * inv; gsw[2 * b + 1] = pe[i1] * inv;
    }
}

// ---------------- transpose+convert: fp32 [Z][R][C] -> bf16 [Z][C][R] ----------------
__global__ __launch_bounds__(256) void k_transpose_cvt(const float* __restrict__ src,
                                                       ushort_t* __restrict__ dst,
                                                       int R, int C) {
    __shared__ float tile[64][65];
    int z = blockIdx.z;
    const float* s = src + (size_t)z * R * C;
    ushort_t* d = dst + (size_t)z * R * C;
    int c0 = blockIdx.x * 64, r0 = blockIdx.y * 64;
    int t = threadIdx.x;
    int tc = (t & 15) * 4, tr = t >> 4;
#pragma unroll
    for (int i = 0; i < 4; ++i) {
        int r = tr + i * 16;
        float4 v = *(const float4*)(s + (size_t)(r0 + r) * C + c0 + tc);
        tile[r][tc] = v.x; tile[r][tc + 1] = v.y; tile[r][tc + 2] = v.z; tile[r][tc + 3] = v.w;
    }
    __syncthreads();
    int wc = t >> 2, wr = (t & 3) * 16;
#pragma unroll
    for (int i = 0; i < 4; ++i) {
        ushort4 o;
        o.x = f2bf(tile[wr + i * 4 + 0][wc]);
        o.y = f2bf(tile[wr + i * 4 + 1][wc]);
        o.z = f2bf(tile[wr + i * 4 + 2][wc]);
        o.w = f2bf(tile[wr + i * 4 + 3][wc]);
        *(ushort4*)(d + (size_t)(c0 + wc) * R + r0 + wr + i * 4) = o;
    }
}

// ---------------- GEMM core: C128x128 += A[M][K] * Bt[N][K]^T ----------------
// BK=64, XOR-swizzled LDS (granule s = kg ^ (row&7)) -> conflict-free ds_read_b128.
// LDS dest of global_load_lds is base + lane*16B (HW rule); swizzle is applied by
// permuting WHICH global 16B-granule each lane fetches.
template <int NSEG, typename Epi>
__device__ __forceinline__ void gemm128(const ushort_t* A0, const ushort_t* A1,
                                        const ushort_t* B0, const ushort_t* B1,
                                        int segK, int m0, int n0, Epi epi) {
    __shared__ ushort_t lA[128 * 64];   // 16 KB, rows of 64 k (128B), swizzled granules
    __shared__ ushort_t lB[128 * 64];   // 16 KB
    const int tid = threadIdx.x;
    const int lane = tid & 63;
    const int wave = tid >> 6;
    const int quad = lane >> 4;         // k-granule within 32-k group
    const int l15 = lane & 15;
    const int sw = l15 & 7;             // reader swizzle key (= row128 & 7)
    const int wm = wave >> 1, wn = wave & 1;

    // staging: wave stages rows [32w, 32w+32) of A and B, 4 chunks of 8 rows each.
    const int srow = 32 * wave + (lane >> 3);                 // global row within tile (chunk 0)
    const int skg = (lane & 7) ^ (lane >> 3);                 // swizzled k-granule to fetch
    ushort_t* la = lA + (size_t)wave * 2048;                  // 32 rows * 64
    ushort_t* lb = lB + (size_t)wave * 2048;

    f32x4 acc[4][4] = {};
    const int steps = segK >> 6;

#pragma unroll 1
    for (int seg = 0; seg < NSEG; ++seg) {
        const ushort_t* A = (NSEG == 2 && seg == 1) ? A1 : A0;
        const ushort_t* B = (NSEG == 2 && seg == 1) ? B1 : B0;
        const size_t ro = (size_t)8 * segK;                   // 8-row stride
        const ushort_t* pa = A + (size_t)(m0 + srow) * segK + skg * 8;
        const ushort_t* pb = B + (size_t)(n0 + srow) * segK + skg * 8;
#pragma unroll 1
        for (int kt = 0; kt < steps; ++kt) {
            gload_lds16(pa,           la);
            gload_lds16(pa +     ro,  la +  512);
            gload_lds16(pa + 2 * ro,  la + 1024);
            gload_lds16(pa + 3 * ro,  la + 1536);
            gload_lds16(pb,           lb);
            gload_lds16(pb +     ro,  lb +  512);
            gload_lds16(pb + 2 * ro,  lb + 1024);
            gload_lds16(pb + 3 * ro,  lb + 1536);
            pa += 64; pb += 64;
            __syncthreads();            // drain vmcnt -> tiles visible
            const bf16x8* pAf = (const bf16x8*)lA;
            const bf16x8* pBf = (const bf16x8*)lB;
#pragma unroll
            for (int h = 0; h < 2; ++h) {
                bf16x8 af[4], bfr[4];
#pragma unroll
                for (int mi = 0; mi < 4; ++mi)
                    af[mi] = pAf[(wm * 64 + mi * 16 + l15) * 8 + ((h * 4 + quad) ^ sw)];
#pragma unroll
                for (int ni = 0; ni < 4; ++ni)
                    bfr[ni] = pBf[(wn * 64 + ni * 16 + l15) * 8 + ((h * 4 + quad) ^ sw)];
#pragma unroll
                for (int mi = 0; mi < 4; ++mi)
#pragma unroll
                    for (int ni = 0; ni < 4; ++ni)
                        acc[mi][ni] = __builtin_amdgcn_mfma_f32_16x16x32_bf16(af[mi], bfr[ni], acc[mi][ni], 0, 0, 0);
            }
            __syncthreads();            // all reads done before restage
        }
    }
    // C/D layout: col = lane&15, row = quad*4 + reg (verified m89/m91)
#pragma unroll
    for (int mi = 0; mi < 4; ++mi)
#pragma unroll
        for (int ni = 0; ni < 4; ++ni)
            epi(m0 + wm * 64 + mi * 16 + quad * 4, n0 + wn * 64 + ni * 16 + l15, acc[mi][ni]);
}

// epilogues
struct EpiGeluStore {
    ushort_t* H; int ldh; const float* bias; float scale;
    __device__ void operator()(int r, int c, f32x4 v) const {
        float bc = bias[c];
#pragma unroll
        for (int i = 0; i < 4; ++i)
            H[(size_t)(r + i) * ldh + c] = f2bf(scale * gelu_tanh(v[i] + bc));
    }
};
struct EpiMainOut {
    float* out; const float* bias; float a;
    __device__ void operator()(int r, int c, f32x4 v) const {
        float bc = bias[c];
#pragma unroll
        for (int i = 0; i < 4; ++i) out[(size_t)(r + i) * 1024 + c] = a * (v[i] + bc);
    }
};
struct EpiExpertOut {
    float* out; const float* b0; const float* b1; float g0, g1;
    __device__ void operator()(int r, int c, f32x4 v) const {
        float bc = g0 * b0[c] + g1 * b1[c];
#pragma unroll
        for (int i = 0; i < 4; ++i) out[(size_t)(r + i) * 1024 + c] += v[i] + bc;
    }
};

// ---------------- phase kernels (all 1D grids, XCD-aware block swizzle: xcd = id&7) ----------------
// B: Hm = gelu(Xbf @ W1mT^T + b1m)   M=16384 N=4096 K=1024, grid 4096
__global__ __launch_bounds__(256) void k_gemm_main1(const ushort_t* __restrict__ Xbf,
                                                    const ushort_t* __restrict__ W1mT,
                                                    const float* __restrict__ b1m,
                                                    ushort_t* __restrict__ Hm) {
    int id = blockIdx.x, xcd = id & 7, slot = id >> 3;        // slot 0..511
    int tm = xcd * 16 + (slot >> 5);                          // 16 tm-rows per XCD
    int tn = slot & 31;
    EpiGeluStore epi{Hm, 4096, b1m, 1.0f};
    gemm128<1>(Xbf, Xbf, W1mT, W1mT, 1024, tm * 128, tn * 128, epi);
}
// C: out = a*(Hm @ W2mT^T + b2m)     M=16384 N=1024 K=4096, grid 1024
__global__ __launch_bounds__(256) void k_gemm_main2(const ushort_t* __restrict__ Hm,
                                                    const ushort_t* __restrict__ W2mT,
                                                    const float* __restrict__ b2m,
                                                    const float* __restrict__ alpha,
                                                    float* __restrict__ out) {
    int id = blockIdx.x, xcd = id & 7, slot = id >> 3;        // slot 0..127
    int tm = xcd * 16 + (slot >> 3);
    int tn = slot & 7;
    float a = fminf(fmaxf(alpha[0], 0.1f), 1.0f);
    EpiMainOut epi{out, b2m, a};
    gemm128<1>(Hm, Hm, W2mT, W2mT, 4096, tm * 128, tn * 128, epi);
}
// D: He[j] = gsw[j]*gelu(Xbf[b] @ W1eT[e]^T + b1e[e])  M=1024 N=4096 K=1024, grid 8192
__global__ __launch_bounds__(256) void k_gemm_exp1(const ushort_t* __restrict__ Xbf,
                                                   const ushort_t* __restrict__ W1eT,
                                                   const float* __restrict__ b1e,
                                                   const int* __restrict__ eidx,
                                                   const float* __restrict__ gsw,
                                                   ushort_t* __restrict__ He) {
    int id = blockIdx.x, xcd = id & 7, slot = id >> 3;        // slot 0..1023
    int j = xcd + 8 * (slot >> 8);                            // 4 assignments per XCD
    int tile = slot & 255;
    int tm = tile >> 5, tn = tile & 31;
    int b = j >> 1;
    int e = eidx[j];
    float gs = gsw[j];
    const ushort_t* A = Xbf + (size_t)b * 1024 * 1024;
    const ushort_t* Bm = W1eT + (size_t)e * 4096 * 1024;
    EpiGeluStore epi{He + (size_t)j * 1024 * 4096, 4096, b1e + (size_t)e * 4096, gs};
    gemm128<1>(A, A, Bm, Bm, 1024, tm * 128, tn * 128, epi);
}
// E: out[b] += sum_k He[b,k] @ W2eT[ek]^T + gs_k*b2e[ek]   M=1024 N=1024 K=2x4096, grid 1024
__global__ __launch_bounds__(256) void k_gemm_exp2(const ushort_t* __restrict__ He,
                                                   const ushort_t* __restrict__ W2eT,
                                                   const float* __restrict__ b2e,
                                                   const int* __restrict__ eidx,
                                                   const float* __restrict__ gsw,
                                                   float* __restrict__ out) {
    int id = blockIdx.x, xcd = id & 7, slot = id >> 3;        // slot 0..127
    int b = xcd + 8 * (slot >> 6);                            // 2 batches per XCD
    int tile = slot & 63;
    int tm = tile >> 3, tn = tile & 7;
    int e0 = eidx[2 * b], e1 = eidx[2 * b + 1];
    EpiExpertOut epi{out + (size_t)b * 1024 * 1024,
                     b2e + (size_t)e0 * 1024, b2e + (size_t)e1 * 1024,
                     gsw[2 * b], gsw[2 * b + 1]};
    gemm128<2>(He + (size_t)(2 * b) * 1024 * 4096, He + (size_t)(2 * b + 1) * 1024 * 4096,
               W2eT + (size_t)e0 * 1024 * 4096, W2eT + (size_t)e1 * 1024 * 4096,
               4096, tm * 128, tn * 128, epi);
}

extern "C" void kernel_launch(void* const* d_in, const int* in_sizes, int n_in,
                              void* d_out, int out_size, void* d_ws, size_t ws_size,
                              hipStream_t stream) {
    const float* x      = (const float*)d_in[0];
    const float* alpha  = (const float*)d_in[1];
    const float* w_gate = (const float*)d_in[2];
    const float* b_gate = (const float*)d_in[3];
    const float* W1m    = (const float*)d_in[4];
    const float* b1m    = (const float*)d_in[5];
    const float* W2m    = (const float*)d_in[6];
    const float* b2m    = (const float*)d_in[7];
    const float* W1e    = (const float*)d_in[8];
    const float* b1e    = (const float*)d_in[9];
    const float* W2e    = (const float*)d_in[10];
    const float* b2e    = (const float*)d_in[11];
    float* out = (float*)d_out;

    char* ws = (char*)d_ws;
    size_t off = 0;
    ushort_t* Xbf  = (ushort_t*)(ws + off); off += (size_t)16384 * 1024 * 2;
    ushort_t* W1mT = (ushort_t*)(ws + off); off += (size_t)4096 * 1024 * 2;
    ushort_t* W2mT = (ushort_t*)(ws + off); off += (size_t)4096 * 1024 * 2;
    ushort_t* W1eT = (ushort_t*)(ws + off); off += (size_t)8 * 4096 * 1024 * 2;
    ushort_t* W2eT = (ushort_t*)(ws + off); off += (size_t)8 * 4096 * 1024 * 2;
    float*    part = (float*)(ws + off);    off += (size_t)16 * 16 * 1024 * 4;
    int*      eidx = (int*)(ws + off);      off += 256;
    float*    gsw  = (float*)(ws + off);    off += 256;
    ushort_t* He   = (ushort_t*)(ws + off);
    ushort_t* Hm   = He;  // alias: Hm dead (after main2) before He written (exp1)
    off += (size_t)32 * 1024 * 4096 * 2;
    if (ws_size < off) return;

    k_convert_x_pool<<<dim3(16, 16), 256, 0, stream>>>(x, Xbf, part);
    k_router<<<16, 256, 0, stream>>>(part, w_gate, b_gate, alpha, eidx, gsw);
    k_transpose_cvt<<<dim3(64, 16, 1), 256, 0, stream>>>(W1m, W1mT, 1024, 4096);
    k_transpose_cvt<<<dim3(16, 64, 1), 256, 0, stream>>>(W2m, W2mT, 4096, 1024);
    k_transpose_cvt<<<dim3(64, 16, 8), 256, 0, stream>>>(W1e, W1eT, 1024, 4096);
    k_transpose_cvt<<<dim3(16, 64, 8), 256, 0, stream>>>(W2e, W2eT, 4096, 1024);
    k_gemm_main1<<<4096, 256, 0, stream>>>(Xbf, W1mT, b1m, Hm);
    k_gemm_main2<<<1024, 256, 0, stream>>>(Hm, W2mT, b2m, alpha, out);
    k_gemm_exp1<<<8192, 256, 0, stream>>>(Xbf, W1eT, b1e, eidx, gsw, He);
    k_gemm_exp2<<<1024, 256, 0, stream>>>(He, W2eT, b2e, eidx, gsw, out);
}

// Round 3
// 1547.822 us; speedup vs baseline: 1.1686x; 1.0171x over previous
//
#include <hip/hip_runtime.h>
#include <hip/hip_bf16.h>
#include <stddef.h>

typedef unsigned short ushort_t;
typedef __bf16 bf16x8 __attribute__((ext_vector_type(8)));
typedef float  f32x4  __attribute__((ext_vector_type(4)));

#define GAS __attribute__((address_space(1)))
#define LAS __attribute__((address_space(3)))

__device__ __forceinline__ ushort_t f2bf(float f) {
    union { float f; unsigned u; } v; v.f = f;
    unsigned r = v.u + 0x7fffu + ((v.u >> 16) & 1u);   // RNE
    return (ushort_t)(r >> 16);
}

// gelu(x) = x * sigmoid(2u), u = 0.79788456*(x + 0.044715 x^3)
// ~6 VALU ops (v_exp_f32 + v_rcp_f32) vs ~30+ for ocml tanhf. exp2 overflow is
// benign: e=inf -> rcp(1+inf)=0 -> gelu=0 (x<<0); e=0 -> gelu=x (x>>0).
__device__ __forceinline__ float gelu_tanh(float x) {
    float u = 0.7978845608028654f * x * (1.0f + 0.044715f * x * x);
    float e = __builtin_amdgcn_exp2f(-2.8853900817779268f * u);   // exp(-2u)
    return x * __builtin_amdgcn_rcpf(1.0f + e);
}

__device__ __forceinline__ void gload_lds16(const ushort_t* g, ushort_t* l) {
    __builtin_amdgcn_global_load_lds((const GAS void*)g, (LAS void*)l, 16, 0, 0);
}

// ---------------- phase A: x fp32 -> bf16, fused mean-pool partials ----------------
__global__ __launch_bounds__(256) void k_convert_x_pool(const float* __restrict__ x,
                                                        ushort_t* __restrict__ Xbf,
                                                        float* __restrict__ part) {
    int b = blockIdx.x, c = blockIdx.y, t = threadIdx.x;
    int d = t * 4;
    const float* xp = x + ((size_t)b * 1024 + (size_t)c * 64) * 1024;
    ushort_t* op = Xbf + ((size_t)b * 1024 + (size_t)c * 64) * 1024;
    float s0 = 0, s1 = 0, s2 = 0, s3 = 0;
    for (int n = 0; n < 64; ++n) {
        float4 v = *(const float4*)(xp + (size_t)n * 1024 + d);
        s0 += v.x; s1 += v.y; s2 += v.z; s3 += v.w;
        ushort4 o; o.x = f2bf(v.x); o.y = f2bf(v.y); o.z = f2bf(v.z); o.w = f2bf(v.w);
        *(ushort4*)(op + (size_t)n * 1024 + d) = o;
    }
    float4 s; s.x = s0; s.y = s1; s.z = s2; s.w = s3;
    *(float4*)(part + ((size_t)b * 16 + c) * 1024 + d) = s;
}

// ---------------- router ----------------
__global__ __launch_bounds__(256) void k_router(const float* __restrict__ part,
                                                const float* __restrict__ w_gate,
                                                const float* __restrict__ b_gate,
                                                const float* __restrict__ alpha,
                                                int* __restrict__ eidx,
                                                float* __restrict__ gsw) {
    __shared__ float red[8 * 256];
    int b = blockIdx.x, t = threadIdx.x;
    float le[8];
#pragma unroll
    for (int e = 0; e < 8; ++e) le[e] = 0.f;
    for (int i = 0; i < 4; ++i) {
        int d = t + i * 256;
        float s = 0.f;
#pragma unroll
        for (int c = 0; c < 16; ++c) s += part[((size_t)b * 16 + c) * 1024 + d];
        s *= (1.0f / 1024.0f);
#pragma unroll
        for (int e = 0; e < 8; ++e) le[e] += s * w_gate[(size_t)d * 8 + e];
    }
#pragma unroll
    for (int e = 0; e < 8; ++e) red[e * 256 + t] = le[e];
    __syncthreads();
    for (int s2 = 128; s2 > 0; s2 >>= 1) {
        if (t < s2)
#pragma unroll
            for (int e = 0; e < 8; ++e) red[e * 256 + t] += red[e * 256 + t + s2];
        __syncthreads();
    }
    if (t == 0) {
        float lg[8];
#pragma unroll
        for (int e = 0; e < 8; ++e) lg[e] = red[e * 256] + b_gate[e];
        float mx = lg[0];
#pragma unroll
        for (int e = 1; e < 8; ++e) mx = fmaxf(mx, lg[e]);
        float pe[8];
#pragma unroll
        for (int e = 0; e < 8; ++e) pe[e] = expf(lg[e] - mx);
        int i0 = 0;
        for (int e = 1; e < 8; ++e) if (pe[e] > pe[i0]) i0 = e;
        int i1 = -1;
        for (int e = 0; e < 8; ++e) { if (e == i0) continue; if (i1 < 0 || pe[e] > pe[i1]) i1 = e; }
        float a = fminf(fmaxf(alpha[0], 0.1f), 1.0f);
        float inv = (1.0f - a) / (pe[i0] + pe[i1]);
        eidx[2 * b] = i0; eidx[2 * b + 1] = i1;
        gsw[2 * b] = pe[i0] * inv; gsw[2 * b + 1] = pe[i1] * inv;
    }
}

// ---------------- transpose+convert: fp32 [Z][R][C] -> bf16 [Z][C][R] ----------------
__global__ __launch_bounds__(256) void k_transpose_cvt(const float* __restrict__ src,
                                                       ushort_t* __restrict__ dst,
                                                       int R, int C) {
    __shared__ float tile[64][65];
    int z = blockIdx.z;
    const float* s = src + (size_t)z * R * C;
    ushort_t* d = dst + (size_t)z * R * C;
    int c0 = blockIdx.x * 64, r0 = blockIdx.y * 64;
    int t = threadIdx.x;
    int tc = (t & 15) * 4, tr = t >> 4;
#pragma unroll
    for (int i = 0; i < 4; ++i) {
        int r = tr + i * 16;
        float4 v = *(const float4*)(s + (size_t)(r0 + r) * C + c0 + tc);
        tile[r][tc] = v.x; tile[r][tc + 1] = v.y; tile[r][tc + 2] = v.z; tile[r][tc + 3] = v.w;
    }
    __syncthreads();
    int wc = t >> 2, wr = (t & 3) * 16;
#pragma unroll
    for (int i = 0; i < 4; ++i) {
        ushort4 o;
        o.x = f2bf(tile[wr + i * 4 + 0][wc]);
        o.y = f2bf(tile[wr + i * 4 + 1][wc]);
        o.z = f2bf(tile[wr + i * 4 + 2][wc]);
        o.w = f2bf(tile[wr + i * 4 + 3][wc]);
        *(ushort4*)(d + (size_t)(c0 + wc) * R + r0 + wr + i * 4) = o;
    }
}

// ---------------- GEMM core: C128x128 += A[M][K] * Bt[N][K]^T ----------------
// BK=64, XOR-swizzled LDS (granule = kg ^ (row&7)) -> 0 bank conflicts (verified R2).
template <int NSEG, typename Epi>
__device__ __forceinline__ void gemm128(const ushort_t* A0, const ushort_t* A1,
                                        const ushort_t* B0, const ushort_t* B1,
                                        int segK, int m0, int n0, Epi epi) {
    __shared__ ushort_t lA[128 * 64];   // 16 KB
    __shared__ ushort_t lB[128 * 64];   // 16 KB
    const int tid = threadIdx.x;
    const int lane = tid & 63;
    const int wave = tid >> 6;
    const int quad = lane >> 4;
    const int l15 = lane & 15;
    const int sw = l15 & 7;
    const int wm = wave >> 1, wn = wave & 1;

    const int srow = 32 * wave + (lane >> 3);
    const int skg = (lane & 7) ^ (lane >> 3);
    ushort_t* la = lA + (size_t)wave * 2048;
    ushort_t* lb = lB + (size_t)wave * 2048;

    f32x4 acc[4][4] = {};
    const int steps = segK >> 6;

#pragma unroll 1
    for (int seg = 0; seg < NSEG; ++seg) {
        const ushort_t* A = (NSEG == 2 && seg == 1) ? A1 : A0;
        const ushort_t* B = (NSEG == 2 && seg == 1) ? B1 : B0;
        const size_t ro = (size_t)8 * segK;
        const ushort_t* pa = A + (size_t)(m0 + srow) * segK + skg * 8;
        const ushort_t* pb = B + (size_t)(n0 + srow) * segK + skg * 8;
#pragma unroll 1
        for (int kt = 0; kt < steps; ++kt) {
            gload_lds16(pa,           la);
            gload_lds16(pa +     ro,  la +  512);
            gload_lds16(pa + 2 * ro,  la + 1024);
            gload_lds16(pa + 3 * ro,  la + 1536);
            gload_lds16(pb,           lb);
            gload_lds16(pb +     ro,  lb +  512);
            gload_lds16(pb + 2 * ro,  lb + 1024);
            gload_lds16(pb + 3 * ro,  lb + 1536);
            pa += 64; pb += 64;
            __syncthreads();
            const bf16x8* pAf = (const bf16x8*)lA;
            const bf16x8* pBf = (const bf16x8*)lB;
#pragma unroll
            for (int h = 0; h < 2; ++h) {
                bf16x8 af[4], bfr[4];
#pragma unroll
                for (int mi = 0; mi < 4; ++mi)
                    af[mi] = pAf[(wm * 64 + mi * 16 + l15) * 8 + ((h * 4 + quad) ^ sw)];
#pragma unroll
                for (int ni = 0; ni < 4; ++ni)
                    bfr[ni] = pBf[(wn * 64 + ni * 16 + l15) * 8 + ((h * 4 + quad) ^ sw)];
#pragma unroll
                for (int mi = 0; mi < 4; ++mi)
#pragma unroll
                    for (int ni = 0; ni < 4; ++ni)
                        acc[mi][ni] = __builtin_amdgcn_mfma_f32_16x16x32_bf16(af[mi], bfr[ni], acc[mi][ni], 0, 0, 0);
            }
            __syncthreads();
        }
    }
#pragma unroll
    for (int mi = 0; mi < 4; ++mi)
#pragma unroll
        for (int ni = 0; ni < 4; ++ni)
            epi(m0 + wm * 64 + mi * 16 + quad * 4, n0 + wn * 64 + ni * 16 + l15, acc[mi][ni]);
}

// epilogues
struct EpiGeluStore {
    ushort_t* H; int ldh; const float* bias; float scale;
    __device__ void operator()(int r, int c, f32x4 v) const {
        float bc = bias[c];
#pragma unroll
        for (int i = 0; i < 4; ++i)
            H[(size_t)(r + i) * ldh + c] = f2bf(scale * gelu_tanh(v[i] + bc));
    }
};
struct EpiMainOut {
    float* out; const float* bias; float a;
    __device__ void operator()(int r, int c, f32x4 v) const {
        float bc = bias[c];
#pragma unroll
        for (int i = 0; i < 4; ++i) out[(size_t)(r + i) * 1024 + c] = a * (v[i] + bc);
    }
};
struct EpiExpertOut {
    float* out; const float* b0; const float* b1; float g0, g1;
    __device__ void operator()(int r, int c, f32x4 v) const {
        float bc = g0 * b0[c] + g1 * b1[c];
#pragma unroll
        for (int i = 0; i < 4; ++i) out[(size_t)(r + i) * 1024 + c] += v[i] + bc;
    }
};

// ---------------- phase kernels ----------------
// All use xcd = id&7 (round-robin dispatch) + 8x8 supertiles so the co-resident
// working set (A 2MB + B 2MB) fits the 4MB per-XCD L2.

// B: Hm = gelu(Xbf @ W1mT^T + b1m)   M=16384 N=4096 K=1024, grid 4096
__global__ __launch_bounds__(256) void k_gemm_main1(const ushort_t* __restrict__ Xbf,
                                                    const ushort_t* __restrict__ W1mT,
                                                    const float* __restrict__ b1m,
                                                    ushort_t* __restrict__ Hm) {
    int id = blockIdx.x, xcd = id & 7, slot = id >> 3;        // slot 0..511
    int g = slot >> 6;                                        // 8 supertiles (2 gm x 4 gn)
    int u = slot & 63;
    int tm = xcd * 16 + (g & 1) * 8 + (u & 7);
    int tn = (g >> 1) * 8 + (u >> 3);
    EpiGeluStore epi{Hm, 4096, b1m, 1.0f};
    gemm128<1>(Xbf, Xbf, W1mT, W1mT, 1024, tm * 128, tn * 128, epi);
}
// C: out = a*(Hm @ W2mT^T + b2m)     M=16384 N=1024 K=4096, grid 1024
__global__ __launch_bounds__(256) void k_gemm_main2(const ushort_t* __restrict__ Hm,
                                                    const ushort_t* __restrict__ W2mT,
                                                    const float* __restrict__ b2m,
                                                    const float* __restrict__ alpha,
                                                    float* __restrict__ out) {
    int id = blockIdx.x, xcd = id & 7, slot = id >> 3;        // slot 0..127
    int g = slot >> 5;                                        // 4 supertiles (4tm x 8tn)
    int u = slot & 31;
    int tm = xcd * 16 + g * 4 + (u & 3);
    int tn = u >> 2;
    float a = fminf(fmaxf(alpha[0], 0.1f), 1.0f);
    EpiMainOut epi{out, b2m, a};
    gemm128<1>(Hm, Hm, W2mT, W2mT, 4096, tm * 128, tn * 128, epi);
}
// D: He[j] = gsw[j]*gelu(Xbf[b] @ W1eT[e]^T + b1e[e])  M=1024 N=4096 K=1024, grid 8192
__global__ __launch_bounds__(256) void k_gemm_exp1(const ushort_t* __restrict__ Xbf,
                                                   const ushort_t* __restrict__ W1eT,
                                                   const float* __restrict__ b1e,
                                                   const int* __restrict__ eidx,
                                                   const float* __restrict__ gsw,
                                                   ushort_t* __restrict__ He) {
    int id = blockIdx.x, xcd = id & 7, slot = id >> 3;        // slot 0..1023
    int j = xcd + 8 * (slot >> 8);                            // 4 assignments per XCD
    int u2 = slot & 255;
    int g = u2 >> 6;                                          // 4 supertiles (8tm x 8tn)
    int u = u2 & 63;
    int tm = u & 7;
    int tn = g * 8 + (u >> 3);
    int b = j >> 1;
    int e = eidx[j];
    float gs = gsw[j];
    const ushort_t* A = Xbf + (size_t)b * 1024 * 1024;
    const ushort_t* Bm = W1eT + (size_t)e * 4096 * 1024;
    EpiGeluStore epi{He + (size_t)j * 1024 * 4096, 4096, b1e + (size_t)e * 4096, gs};
    gemm128<1>(A, A, Bm, Bm, 1024, tm * 128, tn * 128, epi);
}
// E: out[b] += sum_k He[b,k] @ W2eT[ek]^T + gs_k*b2e[ek]   M=1024 N=1024 K=2x4096, grid 1024
__global__ __launch_bounds__(256) void k_gemm_exp2(const ushort_t* __restrict__ He,
                                                   const ushort_t* __restrict__ W2eT,
                                                   const float* __restrict__ b2e,
                                                   const int* __restrict__ eidx,
                                                   const float* __restrict__ gsw,
                                                   float* __restrict__ out) {
    int id = blockIdx.x, xcd = id & 7, slot = id >> 3;        // slot 0..127
    int b = xcd + 8 * (slot >> 6);                            // 2 batches per XCD
    int tile = slot & 63;                                     // all 64 co-resident
    int tm = tile >> 3, tn = tile & 7;
    int e0 = eidx[2 * b], e1 = eidx[2 * b + 1];
    EpiExpertOut epi{out + (size_t)b * 1024 * 1024,
                     b2e + (size_t)e0 * 1024, b2e + (size_t)e1 * 1024,
                     gsw[2 * b], gsw[2 * b + 1]};
    gemm128<2>(He + (size_t)(2 * b) * 1024 * 4096, He + (size_t)(2 * b + 1) * 1024 * 4096,
               W2eT + (size_t)e0 * 1024 * 4096, W2eT + (size_t)e1 * 1024 * 4096,
               4096, tm * 128, tn * 128, epi);
}

extern "C" void kernel_launch(void* const* d_in, const int* in_sizes, int n_in,
                              void* d_out, int out_size, void* d_ws, size_t ws_size,
                              hipStream_t stream) {
    const float* x      = (const float*)d_in[0];
    const float* alpha  = (const float*)d_in[1];
    const float* w_gate = (const float*)d_in[2];
    const float* b_gate = (const float*)d_in[3];
    const float* W1m    = (const float*)d_in[4];
    const float* b1m    = (const float*)d_in[5];
    const float* W2m    = (const float*)d_in[6];
    const float* b2m    = (const float*)d_in[7];
    const float* W1e    = (const float*)d_in[8];
    const float* b1e    = (const float*)d_in[9];
    const float* W2e    = (const float*)d_in[10];
    const float* b2e    = (const float*)d_in[11];
    float* out = (float*)d_out;

    char* ws = (char*)d_ws;
    size_t off = 0;
    ushort_t* Xbf  = (ushort_t*)(ws + off); off += (size_t)16384 * 1024 * 2;
    ushort_t* W1mT = (ushort_t*)(ws + off); off += (size_t)4096 * 1024 * 2;
    ushort_t* W2mT = (ushort_t*)(ws + off); off += (size_t)4096 * 1024 * 2;
    ushort_t* W1eT = (ushort_t*)(ws + off); off += (size_t)8 * 4096 * 1024 * 2;
    ushort_t* W2eT = (ushort_t*)(ws + off); off += (size_t)8 * 4096 * 1024 * 2;
    float*    part = (float*)(ws + off);    off += (size_t)16 * 16 * 1024 * 4;
    int*      eidx = (int*)(ws + off);      off += 256;
    float*    gsw  = (float*)(ws + off);    off += 256;
    ushort_t* He   = (ushort_t*)(ws + off);
    ushort_t* Hm   = He;  // alias: Hm dead (after main2) before He written (exp1)
    off += (size_t)32 * 1024 * 4096 * 2;
    if (ws_size < off) return;

    k_convert_x_pool<<<dim3(16, 16), 256, 0, stream>>>(x, Xbf, part);
    k_router<<<16, 256, 0, stream>>>(part, w_gate, b_gate, alpha, eidx, gsw);
    k_transpose_cvt<<<dim3(64, 16, 1), 256, 0, stream>>>(W1m, W1mT, 1024, 4096);
    k_transpose_cvt<<<dim3(16, 64, 1), 256, 0, stream>>>(W2m, W2mT, 4096, 1024);
    k_transpose_cvt<<<dim3(64, 16, 8), 256, 0, stream>>>(W1e, W1eT, 1024, 4096);
    k_transpose_cvt<<<dim3(16, 64, 8), 256, 0, stream>>>(W2e, W2eT, 4096, 1024);
    k_gemm_main1<<<4096, 256, 0, stream>>>(Xbf, W1mT, b1m, Hm);
    k_gemm_main2<<<1024, 256, 0, stream>>>(Hm, W2mT, b2m, alpha, out);
    k_gemm_exp1<<<8192, 256, 0, stream>>>(Xbf, W1eT, b1e, eidx, gsw, He);
    k_gemm_exp2<<<1024, 256, 0, stream>>>(He, W2eT, b2e, eidx, gsw, out);
}